// Round 5
// baseline (1170.448 us; speedup 1.0000x reference)
//
#include <hip/hip_runtime.h>

#define T_STEPS 512
#define BATCH   1024
#define HID     128
#define BHID    (BATCH * HID)

typedef __attribute__((ext_vector_type(8))) short short8;
typedef __attribute__((ext_vector_type(4))) float f32x4;

__device__ __forceinline__ unsigned cvtpk_bf16(float lo, float hi) {
    unsigned r;
    asm("v_cvt_pk_bf16_f32 %0, %1, %2" : "=v"(r) : "v"(lo), "v"(hi));
    return r;
}
__device__ __forceinline__ float fast_sigmoid(float x) {
    return __builtin_amdgcn_rcpf(1.0f + __builtin_amdgcn_exp2f(-1.442695041f * x));
}
__device__ __forceinline__ float fast_tanh(float x) {
    return 1.0f - 2.0f * __builtin_amdgcn_rcpf(1.0f + __builtin_amdgcn_exp2f(2.885390082f * x));
}
// Raw barrier: wait only LDS ops (lgkm). NO vmcnt drain -> global x prefetch
// stays in flight across the barrier (the whole point of this revision).
__device__ __forceinline__ void barrier_lgkm() {
    __builtin_amdgcn_sched_barrier(0);
    asm volatile("s_waitcnt lgkmcnt(0)" ::: "memory");
    __builtin_amdgcn_sched_barrier(0);
    __builtin_amdgcn_s_barrier();
    __builtin_amdgcn_sched_barrier(0);
}

__global__ __launch_bounds__(512, 2) void gru_scan(
    const float* __restrict__ x, const float* __restrict__ h0,
    const float* __restrict__ w_ih, const float* __restrict__ w_hh,
    const float* __restrict__ b_ih, const float* __restrict__ b_hh,
    const float* __restrict__ w_out, const float* __restrict__ b_out,
    float* __restrict__ out)
{
    __shared__ unsigned hbf[2 * 1024];   // two 4096B bf16[16][128] XOR-swizzled h buffers
    __shared__ float red[16][8];

    const int tid = threadIdx.x;
    const int w   = tid >> 6;
    const int l   = tid & 63;
    const int lm  = l & 15;       // batch row (A) / feature col (D)
    const int lg  = l >> 4;       // K group / D row group
    const int b0  = blockIdx.x << 4;
    const int col = w * 16 + lm;

    // ---- weights -> per-wave register fragments (bf16), biases ----
    short8 wih[3][4], whh[3][4];
    float biasX[3], biasH[3];
    #pragma unroll
    for (int f = 0; f < 3; ++f) {
        const int n = f * 128 + col;
        biasX[f] = b_ih[n];
        biasH[f] = b_hh[n];
        #pragma unroll
        for (int kf = 0; kf < 4; ++kf) {
            const int koff = kf * 32 + lg * 8;
            union { short8 s; unsigned u[4]; } p;
            {
                const float4 a = *(const float4*)(w_ih + n * HID + koff);
                const float4 b = *(const float4*)(w_ih + n * HID + koff + 4);
                p.u[0] = cvtpk_bf16(a.x, a.y); p.u[1] = cvtpk_bf16(a.z, a.w);
                p.u[2] = cvtpk_bf16(b.x, b.y); p.u[3] = cvtpk_bf16(b.z, b.w);
                wih[f][kf] = p.s;
            }
            {
                const float4 a = *(const float4*)(w_hh + n * HID + koff);
                const float4 b = *(const float4*)(w_hh + n * HID + koff + 4);
                p.u[0] = cvtpk_bf16(a.x, a.y); p.u[1] = cvtpk_bf16(a.z, a.w);
                p.u[2] = cvtpk_bf16(b.x, b.y); p.u[3] = cvtpk_bf16(b.z, b.w);
                whh[f][kf] = p.s;
            }
        }
    }

    // ---- precomputed LDS addresses (double buffer picked via +4096 imm) ----
    const unsigned* ha_rd[4];
    #pragma unroll
    for (int kf = 0; kf < 4; ++kf) {
        const int bo = (kf * 64 + lg * 16) ^ ((lm & 7) << 4);
        ha_rd[kf] = &hbf[lm * 64 + (bo >> 2)];
    }
    short* h_wr[4];
    #pragma unroll
    for (int r = 0; r < 4; ++r) {
        const int row = lg * 4 + r;
        const int byte = (col * 2) ^ ((row & 7) << 4);
        h_wr[r] = (short*)hbf + row * 128 + (byte >> 1);
    }

    // ---- per-lane x element offsets (constant); uniform base advances per step ----
    int loA[4], loB[4];
    #pragma unroll
    for (int kf = 0; kf < 4; ++kf) {
        loA[kf] = lm * HID + kf * 32 + lg * 8;
        loB[kf] = loA[kf] + 4;
    }
    const float* xrow = x + (size_t)b0 * HID;

    // ---- init h: f32 regs (own tile) + bf16 swizzled copy in buf0 ----
    float hreg[4];
    #pragma unroll
    for (int r = 0; r < 4; ++r) {
        const int row = lg * 4 + r;
        hreg[r] = h0[(size_t)(b0 + row) * HID + col];
        *(short*)((char*)h_wr[r] + 0) = (short)cvtpk_bf16(hreg[r], hreg[r]);
    }

    // ---- prefetch x[0] ----
    float4 xnA[4], xnB[4];
    #pragma unroll
    for (int kf = 0; kf < 4; ++kf) {
        xnA[kf] = *(const float4*)(xrow + loA[kf]);
        xnB[kf] = *(const float4*)(xrow + loB[kf]);
    }

    __syncthreads();   // prologue barrier (one-time vmcnt drain is fine)

#define GRU_STEP(P, TCUR) do {                                                  \
    /* issue h-frag LDS reads early */                                          \
    short8 ha[4];                                                               \
    _Pragma("unroll")                                                           \
    for (int kf = 0; kf < 4; ++kf)                                              \
        ha[kf] = *(const short8*)((const char*)ha_rd[kf] + (P) * 4096);         \
    /* convert prefetched x (waits on last step's loads; ~1 step old) */        \
    short8 xa[4];                                                               \
    _Pragma("unroll")                                                           \
    for (int kf = 0; kf < 4; ++kf) {                                            \
        union { short8 s; unsigned u[4]; } p;                                   \
        p.u[0] = cvtpk_bf16(xnA[kf].x, xnA[kf].y);                              \
        p.u[1] = cvtpk_bf16(xnA[kf].z, xnA[kf].w);                              \
        p.u[2] = cvtpk_bf16(xnB[kf].x, xnB[kf].y);                              \
        p.u[3] = cvtpk_bf16(xnB[kf].z, xnB[kf].w);                              \
        xa[kf] = p.s;                                                           \
    }                                                                           \
    /* issue x loads for next step (ride across the raw barrier) */             \
    {                                                                           \
        const int tn = ((TCUR) + 1 < T_STEPS) ? (TCUR) + 1 : (TCUR);            \
        const float* xt = xrow + (size_t)tn * BHID;                             \
        _Pragma("unroll")                                                       \
        for (int kf = 0; kf < 4; ++kf) {                                        \
            xnA[kf] = *(const float4*)(xt + loA[kf]);                           \
            xnB[kf] = *(const float4*)(xt + loB[kf]);                           \
        }                                                                       \
    }                                                                           \
    /* MFMA: 3 gates x (x-part, h-part) */                                      \
    f32x4 accX[3], accH[3];                                                     \
    _Pragma("unroll")                                                           \
    for (int f = 0; f < 3; ++f) {                                               \
        accX[f] = (f32x4){biasX[f], biasX[f], biasX[f], biasX[f]};              \
        accH[f] = (f32x4){biasH[f], biasH[f], biasH[f], biasH[f]};              \
        _Pragma("unroll")                                                       \
        for (int kf = 0; kf < 4; ++kf) {                                        \
            accX[f] = __builtin_amdgcn_mfma_f32_16x16x32_bf16(xa[kf], wih[f][kf], accX[f], 0, 0, 0); \
            accH[f] = __builtin_amdgcn_mfma_f32_16x16x32_bf16(ha[kf], whh[f][kf], accH[f], 0, 0, 0); \
        }                                                                       \
    }                                                                           \
    /* gates + h update in registers; bf16 h to other buffer */                 \
    _Pragma("unroll")                                                           \
    for (int r = 0; r < 4; ++r) {                                               \
        const float pr = accX[0][r] + accH[0][r];                               \
        const float pz = accX[1][r] + accH[1][r];                               \
        const float rr = fast_sigmoid(pr);                                      \
        const float zz = fast_sigmoid(pz);                                      \
        const float nn = fast_tanh(accX[2][r] + rr * accH[2][r]);               \
        const float hn = nn + zz * (hreg[r] - nn);                              \
        hreg[r] = hn;                                                           \
        *(short*)((char*)h_wr[r] + ((P) ^ 1) * 4096) = (short)cvtpk_bf16(hn, hn); \
    }                                                                           \
    barrier_lgkm();                                                             \
} while (0)

    #pragma unroll 1
    for (int t = 0; t < T_STEPS; t += 2) {
        GRU_STEP(0, t);
        GRU_STEP(1, t + 1);
    }
#undef GRU_STEP

    // ---- output projection ----
    {
        const float wv = w_out[col];
        float s0 = hreg[0] * wv, s1 = hreg[1] * wv, s2 = hreg[2] * wv, s3 = hreg[3] * wv;
        #pragma unroll
        for (int mask = 8; mask >= 1; mask >>= 1) {
            s0 += __shfl_xor(s0, mask);
            s1 += __shfl_xor(s1, mask);
            s2 += __shfl_xor(s2, mask);
            s3 += __shfl_xor(s3, mask);
        }
        if (lm == 0) {
            red[lg * 4 + 0][w] = s0;
            red[lg * 4 + 1][w] = s1;
            red[lg * 4 + 2][w] = s2;
            red[lg * 4 + 3][w] = s3;
        }
    }
    __syncthreads();
    if (tid < 16) {
        float acc = b_out[0];
        #pragma unroll
        for (int j = 0; j < 8; ++j) acc += red[tid][j];
        out[b0 + tid] = acc;
    }
}

extern "C" void kernel_launch(void* const* d_in, const int* in_sizes, int n_in,
                              void* d_out, int out_size, void* d_ws, size_t ws_size,
                              hipStream_t stream) {
    const float* x     = (const float*)d_in[0];
    const float* h0    = (const float*)d_in[1];
    const float* w_ih  = (const float*)d_in[2];
    const float* w_hh  = (const float*)d_in[3];
    const float* b_ih  = (const float*)d_in[4];
    const float* b_hh  = (const float*)d_in[5];
    const float* w_out = (const float*)d_in[6];
    const float* b_out = (const float*)d_in[7];
    gru_scan<<<64, 512, 0, stream>>>(x, h0, w_ih, w_hh, b_ih, b_hh, w_out, b_out, (float*)d_out);
}